// Round 6
// baseline (383.983 us; speedup 1.0000x reference)
//
#include <hip/hip_runtime.h>
#include <math.h>

constexpr int Bc = 2, Lc = 256, DMc = 256, Hc = 8, DHc = 32;
constexpr float LOG2E = 1.4426950408889634f;
constexpr float NEGC  = -0.72134752044448f;       // -log2e/2
constexpr float RSQRT_DH = 0.17677669529663687f;  // 1/sqrt(32)
#define EXP2 __builtin_amdgcn_exp2f
#define RCP  __builtin_amdgcn_rcpf

// workspace layout (float offsets)
constexpr int W_Q  = 0;         // 131072
constexpr int W_K  = 131072;    // 131072
constexpr int W_V  = 262144;    // 131072
constexpr int W_AO = 393216;    // 131072
constexpr int W_GR = 524288;    // 1048576 (g_rel -> logits)
constexpr int W_PM = 1572864;   // 16384 chunk max
constexpr int W_PS = 1589248;   // 16384 chunk sumexp
constexpr int W_CNT= 1605632;   // 8 u32 barrier counters (zeroed by kA)

// ---------------------------------------------------------------------------
template<int R, int PER>
__device__ __forceinline__ void stage_tile(const float* __restrict__ src, int ld,
                                           int row0, int k0, float* __restrict__ dst, int tid) {
    int row = tid / (16 / PER);
    int cb = (tid % (16 / PER)) * PER;
    const float* g = src + (size_t)(row0 + row) * ld + k0 + cb;
    float v[PER];
    #pragma unroll
    for (int u = 0; u < PER; ++u) v[u] = g[u];
    #pragma unroll
    for (int u = 0; u < PER; ++u) dst[(cb + u) * (R + 1) + row] = v[u];
}

__device__ __forceinline__ void gemm32(const float* __restrict__ A, const float* __restrict__ W,
                                       float* __restrict__ C, const float* __restrict__ bias,
                                       float sc, int m0, int n0, float* smem) {
    float* As = smem;
    float* Ws = smem + 16 * 33;
    int tid = threadIdx.x;
    int tx = tid & 15, ty = tid >> 4;
    float acc[2][2] = {};
    for (int k0 = 0; k0 < 256; k0 += 16) {
        stage_tile<32, 2>(A, 256, m0, k0, As, tid);
        stage_tile<32, 2>(W, 256, n0, k0, Ws, tid);
        __syncthreads();
        #pragma unroll
        for (int k = 0; k < 16; ++k) {
            float a0 = As[k * 33 + ty * 2], a1 = As[k * 33 + ty * 2 + 1];
            float w0 = Ws[k * 33 + tx * 2], w1 = Ws[k * 33 + tx * 2 + 1];
            acc[0][0] = fmaf(a0, w0, acc[0][0]);
            acc[0][1] = fmaf(a0, w1, acc[0][1]);
            acc[1][0] = fmaf(a1, w0, acc[1][0]);
            acc[1][1] = fmaf(a1, w1, acc[1][1]);
        }
        __syncthreads();
    }
    #pragma unroll
    for (int u = 0; u < 2; ++u)
        #pragma unroll
        for (int v = 0; v < 2; ++v) {
            float o = acc[u][v] * sc;
            if (bias) o += bias[n0 + tx * 2 + v];
            C[(size_t)(m0 + ty * 2 + u) * DMc + n0 + tx * 2 + v] = o;
        }
}

// ===========================================================================
// kA: blocks [0,384) QKV gemm, [384,2560) g_rel. Block 0 zeroes barrier
// counters for kTail (stream-ordered: kA fully completes before kTail).
// ===========================================================================
__global__ void __launch_bounds__(256) kA(
    const float* __restrict__ x, const float* __restrict__ t,
    const float* __restrict__ WQ, const float* __restrict__ WK, const float* __restrict__ WV,
    const float* __restrict__ mu_r, const float* __restrict__ sg_r, const float* __restrict__ w_r,
    float* __restrict__ ws)
{
    __shared__ float smem[1088];
    int bx = blockIdx.x;
    int tid = threadIdx.x;
    if (bx < 384) {
        if (bx == 0 && tid < 8)
            __hip_atomic_store((unsigned*)(ws + W_CNT) + tid, 0u,
                               __ATOMIC_RELAXED, __HIP_MEMORY_SCOPE_AGENT);
        int z = bx >> 7, r = bx & 127;
        int m0 = (r >> 3) * 32, n0 = (r & 7) * 32;
        const float* W = (z == 0) ? WQ : (z == 1) ? WK : WV;
        float* C = ws + ((z == 0) ? W_Q : (z == 1) ? W_K : W_V);
        gemm32(x, W, C, nullptr, (z == 0) ? RSQRT_DH : 1.0f, m0, n0, smem);
        return;
    }
    int idx = bx - 384;
    int h = idx & 7, b = (idx >> 3) & 1, p = idx >> 4;
    {   // ns2[512] = -log2e/(2*sigma^2)
        float2 s2 = *(const float2*)(sg_r + h * 512 + tid * 2);
        float2 o;
        o.x = NEGC / (s2.x * s2.x);
        o.y = NEGC / (s2.y * s2.y);
        *(float2*)(smem + tid * 2) = o;
    }
    __syncthreads();
    int ti = 0;
    for (;; ++ti) { int c = 16 - ti; if (p < c) break; p -= c; }
    int tj = ti + p;
    int di = tid >> 4, dj = tid & 15;
    int i = ti * 16 + di, j = tj * 16 + dj;
    float4 t_i = *(const float4*)(t + (b * Lc + i) * 4);
    float4 t_j = *(const float4*)(t + (b * Lc + j) * 4);
    float tr[4] = {fabsf(t_i.x - t_j.x), fabsf(t_i.y - t_j.y),
                   fabsf(t_i.z - t_j.z), fabsf(t_i.w - t_j.w)};
    float a0 = 0.f, a1 = 0.f, a2 = 0.f, a3 = 0.f;
    #pragma unroll
    for (int tg = 0; tg < 4; ++tg) {
        const float* muB = mu_r + h * 512 + tg * 4;
        const float* wB  = w_r  + h * 512 + tg * 4;
        const float* nsB = smem + tg * 4;
        float tv = tr[tg];
        #pragma unroll 4
        for (int d = 0; d < 32; ++d) {
            float4 m4 = *(const float4*)(muB + d * 16);
            float4 w4 = *(const float4*)(wB  + d * 16);
            float4 n4 = *(const float4*)(nsB + d * 16);
            float d0 = tv - m4.x; a0 = fmaf(w4.x, EXP2(d0 * d0 * n4.x), a0);
            float d1 = tv - m4.y; a1 = fmaf(w4.y, EXP2(d1 * d1 * n4.y), a1);
            float d2 = tv - m4.z; a2 = fmaf(w4.z, EXP2(d2 * d2 * n4.z), a2);
            float d3 = tv - m4.w; a3 = fmaf(w4.w, EXP2(d3 * d3 * n4.w), a3);
        }
    }
    float g = ((a0 + a1) + (a2 + a3)) * (1.0f / 32.0f);
    float* gb = ws + W_GR + (size_t)(b * Hc + h) * (Lc * Lc);
    gb[i * Lc + j] = g;
    if (ti != tj) {
        float* lt = smem + 544;
        __syncthreads();
        lt[di * 17 + dj] = g;
        __syncthreads();
        gb[(tj * 16 + di) * Lc + (ti * 16 + dj)] = lt[dj * 17 + di];
    }
}

// ===========================================================================
// kTail: grid 1024, __launch_bounds__(256,4) + 34.5KB LDS -> exactly 4
// blocks/CU co-resident (1024 total) => manual grid barrier is safe.
//   T0 (1024 blk = it x bh x jc): gabs + S,P + modulation -> logits (GR
//       in-place) + per-(row,chunk) softmax max/sumexp partials
//   T1 (512 blk = it x bh x d-half): finalize softmax, probs, PV -> AO
//   T2 (128 blk): out = AO @ WO^T + bO
// ===========================================================================
__device__ __forceinline__ void gridbar(unsigned* cnt, unsigned nb) {
    __syncthreads();
    if (threadIdx.x == 0) {
        __threadfence();
        __hip_atomic_fetch_add(cnt, 1u, __ATOMIC_ACQ_REL, __HIP_MEMORY_SCOPE_AGENT);
        long g = 0;
        while (__hip_atomic_load(cnt, __ATOMIC_ACQUIRE, __HIP_MEMORY_SCOPE_AGENT) < nb) {
            __builtin_amdgcn_s_sleep(2);
            if (++g > (1L << 22)) break;   // escape valve: fail visibly, never hang
        }
        __threadfence();
    }
    __syncthreads();
}

__global__ void __launch_bounds__(256, 4) kTail(
    const float* __restrict__ x, const float* __restrict__ t,
    const float* __restrict__ WO, const float* __restrict__ bO,
    const float* __restrict__ mu_a, const float* __restrict__ sg_a, const float* __restrict__ w_a,
    const float* __restrict__ alpha, const float* __restrict__ beta, const float* __restrict__ gamma,
    float* __restrict__ ws, float* __restrict__ out)
{
    __shared__ float sm[8832];    // 34.5 KB
    const float* Q = ws + W_Q;
    const float* K = ws + W_K;
    const float* V = ws + W_V;
    float* GR = ws + W_GR;
    float* PM = ws + W_PM;
    float* PS = ws + W_PS;
    unsigned* CNT = (unsigned*)(ws + W_CNT);
    int v = blockIdx.x, tid = threadIdx.x;
    int ty = tid >> 4, tx = tid & 15;

    // -------------------- T0 --------------------
    {
        int it = v & 15, bh = (v >> 4) & 15, jc = v >> 8;
        int b = bh >> 3, h = bh & 7;
        int i0 = it * 16, j0 = jc * 64;
        float* sQ  = sm;          // 32x17
        float* sXi = sm + 544;    // 32x17
        float* sKt = sm + 1088;   // 32x68
        float* sXt = sm + 3264;   // 32x68
        float* red = sm + 5440;   // 16x17
        float* sGA = sm + 5712;   // 16
        {   // stage Q^T / Xi^T
            int tt = tid & 127, r = tt >> 3, c4 = (tt & 7) * 4;
            const float* src = (tid < 128)
                ? (Q + ((size_t)(b * Lc + i0 + r) * DMc + h * DHc + c4))
                : (x + ((size_t)(b * Lc + i0 + r) * DMc + h * DHc + c4));
            float* dst = (tid < 128) ? sQ : sXi;
            float4 val = *(const float4*)src;
            dst[(c4 + 0) * 17 + r] = val.x;
            dst[(c4 + 1) * 17 + r] = val.y;
            dst[(c4 + 2) * 17 + r] = val.z;
            dst[(c4 + 3) * 17 + r] = val.w;
        }
        {   // gabs partial: thread (row=ty, group=tx) does 32 evals
            float4 t4 = *(const float4*)(t + (size_t)(b * Lc + i0 + ty) * 4);
            const float* muB = mu_a + h * 512 + tx * 32;
            const float* sgB = sg_a + h * 512 + tx * 32;
            const float* wB  = w_a  + h * 512 + tx * 32;
            float part = 0.f;
            #pragma unroll
            for (int q = 0; q < 8; ++q) {
                float tv = ((q & 3) == 0) ? t4.x : ((q & 3) == 1) ? t4.y
                         : ((q & 3) == 2) ? t4.z : t4.w;
                float4 m4 = *(const float4*)(muB + q * 4);
                float4 s4 = *(const float4*)(sgB + q * 4);
                float4 w4 = *(const float4*)(wB  + q * 4);
                float d0 = (tv - m4.x) * RCP(s4.x);
                float d1 = (tv - m4.y) * RCP(s4.y);
                float d2 = (tv - m4.z) * RCP(s4.z);
                float d3 = (tv - m4.w) * RCP(s4.w);
                part = fmaf(w4.x, EXP2(d0 * d0 * NEGC), part);
                part = fmaf(w4.y, EXP2(d1 * d1 * NEGC), part);
                part = fmaf(w4.z, EXP2(d2 * d2 * NEGC), part);
                part = fmaf(w4.w, EXP2(d3 * d3 * NEGC), part);
            }
            red[ty * 17 + tx] = part;
        }
        __syncthreads();
        if (tid < 16) {
            float s = 0.f;
            #pragma unroll
            for (int q = 0; q < 16; ++q) s += red[tid * 17 + q];
            sGA[tid] = s * (1.0f / 32.0f);
        }
        {   // stage K^T / X^T for this j-chunk
            int r = tid >> 3, c4 = (tid & 7) * 4;
            #pragma unroll
            for (int uu = 0; uu < 2; ++uu) {
                int rr = r + uu * 32;
                float4 kv = *(const float4*)(K + ((size_t)(b * Lc + j0 + rr) * DMc + h * DHc + c4));
                float4 xv = *(const float4*)(x + ((size_t)(b * Lc + j0 + rr) * DMc + h * DHc + c4));
                sKt[(c4 + 0) * 68 + rr] = kv.x;
                sKt[(c4 + 1) * 68 + rr] = kv.y;
                sKt[(c4 + 2) * 68 + rr] = kv.z;
                sKt[(c4 + 3) * 68 + rr] = kv.w;
                sXt[(c4 + 0) * 68 + rr] = xv.x;
                sXt[(c4 + 1) * 68 + rr] = xv.y;
                sXt[(c4 + 2) * 68 + rr] = xv.z;
                sXt[(c4 + 3) * 68 + rr] = xv.w;
            }
        }
        __syncthreads();
        float accS[4] = {}, accP[4] = {};
        #pragma unroll 4
        for (int k = 0; k < 32; ++k) {
            float qa = sQ[k * 17 + ty];
            float xa = sXi[k * 17 + ty];
            float4 kb = *(const float4*)(sKt + k * 68 + tx * 4);
            float4 xb = *(const float4*)(sXt + k * 68 + tx * 4);
            accS[0] = fmaf(qa, kb.x, accS[0]);
            accS[1] = fmaf(qa, kb.y, accS[1]);
            accS[2] = fmaf(qa, kb.z, accS[2]);
            accS[3] = fmaf(qa, kb.w, accS[3]);
            accP[0] = fmaf(xa, xb.x, accP[0]);
            accP[1] = fmaf(xa, xb.y, accP[1]);
            accP[2] = fmaf(xa, xb.z, accP[2]);
            accP[3] = fmaf(xa, xb.w, accP[3]);
        }
        float la = alpha[h], lb = beta[h], lg = gamma[h];
        float ca = 2.0f * la * sGA[ty];
        float* gaddr = GR + (size_t)bh * (Lc * Lc) + (size_t)(i0 + ty) * Lc + j0 + tx * 4;
        float4 gr = *(const float4*)gaddr;
        float4 o;
        o.x = accS[0] * fmaf(accP[0], fmaf(lb, gr.x, ca), lg);
        o.y = accS[1] * fmaf(accP[1], fmaf(lb, gr.y, ca), lg);
        o.z = accS[2] * fmaf(accP[2], fmaf(lb, gr.z, ca), lg);
        o.w = accS[3] * fmaf(accP[3], fmaf(lb, gr.w, ca), lg);
        *(float4*)gaddr = o;
        // chunk softmax partials (16-lane groups share a row)
        float mc = fmaxf(fmaxf(o.x, o.y), fmaxf(o.z, o.w));
        #pragma unroll
        for (int s = 1; s < 16; s <<= 1) mc = fmaxf(mc, __shfl_xor(mc, s, 64));
        float se = EXP2((o.x - mc) * LOG2E) + EXP2((o.y - mc) * LOG2E)
                 + EXP2((o.z - mc) * LOG2E) + EXP2((o.w - mc) * LOG2E);
        #pragma unroll
        for (int s = 1; s < 16; s <<= 1) se += __shfl_xor(se, s, 64);
        if (tx == 0) {
            int idx = ((bh * 16 + it) * 16 + ty) * 4 + jc;
            PM[idx] = mc;
            PS[idx] = se;
        }
    }
    gridbar(CNT + 0, 1024);

    // -------------------- T1 --------------------
    if (v < 512) {
        int it = v & 15, bh = (v >> 4) & 15, half = v >> 8;
        int b = bh >> 3, h = bh & 7;
        int i0 = it * 16;
        float* sP = sm;           // 16x264
        float* sV = sm + 4224;    // 256x17
        {   // finalize row stats + write probs
            int idx4 = ((bh * 16 + it) * 16 + ty) * 4;
            float4 pm = *(const float4*)(PM + idx4);
            float4 ps = *(const float4*)(PS + idx4);
            float m = fmaxf(fmaxf(pm.x, pm.y), fmaxf(pm.z, pm.w));
            float s = ps.x * EXP2((pm.x - m) * LOG2E) + ps.y * EXP2((pm.y - m) * LOG2E)
                    + ps.z * EXP2((pm.z - m) * LOG2E) + ps.w * EXP2((pm.w - m) * LOG2E);
            float rs = 1.0f / s;
            const float* lrow = GR + (size_t)bh * (Lc * Lc) + (size_t)(i0 + ty) * Lc + tx * 16;
            float* prow = sP + ty * 264 + tx * 16;
            #pragma unroll
            for (int q = 0; q < 4; ++q) {
                float4 l4 = *(const float4*)(lrow + q * 4);
                float4 e;
                e.x = EXP2((l4.x - m) * LOG2E) * rs;
                e.y = EXP2((l4.y - m) * LOG2E) * rs;
                e.z = EXP2((l4.z - m) * LOG2E) * rs;
                e.w = EXP2((l4.w - m) * LOG2E) * rs;
                *(float4*)(prow + q * 4) = e;
            }
        }
        {   // stage V 16-dim half-slice for all 256 j
            int r = tid >> 2, c4 = (tid & 3) * 4;
            #pragma unroll
            for (int u = 0; u < 4; ++u) {
                int j = r + u * 64;
                float4 vv = *(const float4*)(V + ((size_t)(b * Lc + j) * DMc
                                                  + h * DHc + half * 16 + c4));
                sV[j * 17 + c4 + 0] = vv.x;
                sV[j * 17 + c4 + 1] = vv.y;
                sV[j * 17 + c4 + 2] = vv.z;
                sV[j * 17 + c4 + 3] = vv.w;
            }
        }
        __syncthreads();
        {   // PV: thread (row=ty, d=tx)
            float a0 = 0.f, a1 = 0.f, a2 = 0.f, a3 = 0.f;
            #pragma unroll 4
            for (int j4 = 0; j4 < 256; j4 += 4) {
                float4 p4 = *(const float4*)(sP + ty * 264 + j4);
                a0 = fmaf(p4.x, sV[(j4 + 0) * 17 + tx], a0);
                a1 = fmaf(p4.y, sV[(j4 + 1) * 17 + tx], a1);
                a2 = fmaf(p4.z, sV[(j4 + 2) * 17 + tx], a2);
                a3 = fmaf(p4.w, sV[(j4 + 3) * 17 + tx], a3);
            }
            ws[W_AO + (size_t)(b * Lc + i0 + ty) * DMc + h * DHc + half * 16 + tx] =
                (a0 + a1) + (a2 + a3);
        }
    }
    gridbar(CNT + 1, 1024);

    // -------------------- T2 --------------------
    if (v < 128) {
        int m0 = (v & 15) * 32, n0 = (v >> 4) * 32;
        gemm32(ws + W_AO, WO, out, bO, 1.0f, m0, n0, sm);
    }
}

// ===========================================================================
extern "C" void kernel_launch(void* const* d_in, const int* in_sizes, int n_in,
                              void* d_out, int out_size, void* d_ws, size_t ws_size,
                              hipStream_t stream) {
    (void)in_sizes; (void)n_in; (void)out_size; (void)ws_size;
    const float* x      = (const float*)d_in[0];
    const float* t      = (const float*)d_in[1];
    const float* WQ     = (const float*)d_in[2];
    const float* WK     = (const float*)d_in[3];
    const float* WV     = (const float*)d_in[4];
    const float* WO     = (const float*)d_in[5];
    const float* bO     = (const float*)d_in[6];
    const float* mu_abs = (const float*)d_in[7];
    const float* sg_abs = (const float*)d_in[8];
    const float* w_abs  = (const float*)d_in[9];
    const float* mu_rel = (const float*)d_in[10];
    const float* sg_rel = (const float*)d_in[11];
    const float* w_rel  = (const float*)d_in[12];
    const float* alpha  = (const float*)d_in[13];
    const float* beta   = (const float*)d_in[14];
    const float* gamma  = (const float*)d_in[15];
    float* out = (float*)d_out;
    float* ws = (float*)d_ws;

    kA<<<dim3(2560), dim3(256), 0, stream>>>(x, t, WQ, WK, WV,
                                             mu_rel, sg_rel, w_rel, ws);
    kTail<<<dim3(1024), dim3(256), 0, stream>>>(x, t, WO, bO,
                                                mu_abs, sg_abs, w_abs,
                                                alpha, beta, gamma, ws, out);
}

// Round 7
// 178.857 us; speedup vs baseline: 2.1469x; 2.1469x over previous
//
#include <hip/hip_runtime.h>
#include <math.h>

constexpr int Bc = 2, Lc = 256, DMc = 256, Hc = 8, DHc = 32;
constexpr float LOG2E = 1.4426950408889634f;
constexpr float NEGC  = -0.72134752044448f;       // -log2e/2
constexpr float RSQRT_DH = 0.17677669529663687f;  // 1/sqrt(32)
#define EXP2 __builtin_amdgcn_exp2f
#define RCP  __builtin_amdgcn_rcpf

// workspace layout (float offsets)
constexpr int W_Q  = 0;         // 131072
constexpr int W_K  = 131072;    // 131072
constexpr int W_V  = 262144;    // 131072
constexpr int W_AO = 393216;    // 131072
constexpr int W_GA = 524288;    // 4096
constexpr int W_GR = 528384;    // 1048576 (g_rel -> logits)

// ---------------------------------------------------------------------------
template<int R, int PER>
__device__ __forceinline__ void stage_tile(const float* __restrict__ src, int ld,
                                           int row0, int k0, float* __restrict__ dst, int tid) {
    int row = tid / (16 / PER);
    int cb = (tid % (16 / PER)) * PER;
    const float* g = src + (size_t)(row0 + row) * ld + k0 + cb;
    float v[PER];
    #pragma unroll
    for (int u = 0; u < PER; ++u) v[u] = g[u];
    #pragma unroll
    for (int u = 0; u < PER; ++u) dst[(cb + u) * (R + 1) + row] = v[u];
}

__device__ __forceinline__ void gemm32(const float* __restrict__ A, const float* __restrict__ W,
                                       float* __restrict__ C, const float* __restrict__ bias,
                                       float sc, int m0, int n0, float* smem) {
    float* As = smem;
    float* Ws = smem + 16 * 33;
    int tid = threadIdx.x;
    int tx = tid & 15, ty = tid >> 4;
    float acc[2][2] = {};
    for (int k0 = 0; k0 < 256; k0 += 16) {
        stage_tile<32, 2>(A, 256, m0, k0, As, tid);
        stage_tile<32, 2>(W, 256, n0, k0, Ws, tid);
        __syncthreads();
        #pragma unroll
        for (int k = 0; k < 16; ++k) {
            float a0 = As[k * 33 + ty * 2], a1 = As[k * 33 + ty * 2 + 1];
            float w0 = Ws[k * 33 + tx * 2], w1 = Ws[k * 33 + tx * 2 + 1];
            acc[0][0] = fmaf(a0, w0, acc[0][0]);
            acc[0][1] = fmaf(a0, w1, acc[0][1]);
            acc[1][0] = fmaf(a1, w0, acc[1][0]);
            acc[1][1] = fmaf(a1, w1, acc[1][1]);
        }
        __syncthreads();
    }
    #pragma unroll
    for (int u = 0; u < 2; ++u)
        #pragma unroll
        for (int v = 0; v < 2; ++v) {
            float o = acc[u][v] * sc;
            if (bias) o += bias[n0 + tx * 2 + v];
            C[(size_t)(m0 + ty * 2 + u) * DMc + n0 + tx * 2 + v] = o;
        }
}

// ===========================================================================
// kA: [0,384) QKV gemm, [384,448) g_abs, [448,2624) g_rel.
// ===========================================================================
__global__ void __launch_bounds__(256) kA(
    const float* __restrict__ x, const float* __restrict__ t,
    const float* __restrict__ WQ, const float* __restrict__ WK, const float* __restrict__ WV,
    const float* __restrict__ mu_a, const float* __restrict__ sg_a, const float* __restrict__ w_a,
    const float* __restrict__ mu_r, const float* __restrict__ sg_r, const float* __restrict__ w_r,
    float* __restrict__ ws)
{
    __shared__ float smem[1088];
    int bx = blockIdx.x;
    int tid = threadIdx.x;
    if (bx < 384) {
        int z = bx >> 7, r = bx & 127;
        int m0 = (r >> 3) * 32, n0 = (r & 7) * 32;
        const float* W = (z == 0) ? WQ : (z == 1) ? WK : WV;
        float* C = ws + ((z == 0) ? W_Q : (z == 1) ? W_K : W_V);
        gemm32(x, W, C, nullptr, (z == 0) ? RSQRT_DH : 1.0f, m0, n0, smem);
        return;
    }
    if (bx < 448) {   // g_abs
        int idx = bx - 384;
        int h = idx & 7, b = (idx >> 3) & 1, q = idx >> 4;
        {
            float2 s2 = *(const float2*)(sg_a + h * 512 + tid * 2);
            float2 o;
            o.x = NEGC / (s2.x * s2.x);
            o.y = NEGC / (s2.y * s2.y);
            *(float2*)(smem + tid * 2) = o;
        }
        __syncthreads();
        int lane = tid & 63, tg = tid >> 6;
        int i = q * 64 + lane;
        float tv = t[(b * Lc + i) * 4 + tg];
        const float* muB = mu_a + h * 512 + tg * 4;
        const float* wB  = w_a  + h * 512 + tg * 4;
        const float* nsB = smem + tg * 4;
        float acc = 0.f;
        #pragma unroll 4
        for (int d = 0; d < 32; ++d) {
            float4 m4 = *(const float4*)(muB + d * 16);
            float4 w4 = *(const float4*)(wB  + d * 16);
            float4 n4 = *(const float4*)(nsB + d * 16);
            float d0 = tv - m4.x; acc = fmaf(w4.x, EXP2(d0 * d0 * n4.x), acc);
            float d1 = tv - m4.y; acc = fmaf(w4.y, EXP2(d1 * d1 * n4.y), acc);
            float d2 = tv - m4.z; acc = fmaf(w4.z, EXP2(d2 * d2 * n4.z), acc);
            float d3 = tv - m4.w; acc = fmaf(w4.w, EXP2(d3 * d3 * n4.w), acc);
        }
        float* red = smem + 544;   // 4x64
        red[tg * 64 + lane] = acc;
        __syncthreads();
        if (tid < 64)
            ws[W_GA + (b * Hc + h) * Lc + q * 64 + lane] =
                (red[lane] + red[64 + lane] + red[128 + lane] + red[192 + lane]) * (1.0f / 32.0f);
        return;
    }
    int idx = bx - 448;
    int h = idx & 7, b = (idx >> 3) & 1, p = idx >> 4;
    {   // ns2[512] = -log2e/(2*sigma^2)
        float2 s2 = *(const float2*)(sg_r + h * 512 + tid * 2);
        float2 o;
        o.x = NEGC / (s2.x * s2.x);
        o.y = NEGC / (s2.y * s2.y);
        *(float2*)(smem + tid * 2) = o;
    }
    __syncthreads();
    int ti = 0;
    for (;; ++ti) { int c = 16 - ti; if (p < c) break; p -= c; }
    int tj = ti + p;
    int di = tid >> 4, dj = tid & 15;
    int i = ti * 16 + di, j = tj * 16 + dj;
    float4 t_i = *(const float4*)(t + (b * Lc + i) * 4);
    float4 t_j = *(const float4*)(t + (b * Lc + j) * 4);
    float tr[4] = {fabsf(t_i.x - t_j.x), fabsf(t_i.y - t_j.y),
                   fabsf(t_i.z - t_j.z), fabsf(t_i.w - t_j.w)};
    float a0 = 0.f, a1 = 0.f, a2 = 0.f, a3 = 0.f;
    #pragma unroll
    for (int tg = 0; tg < 4; ++tg) {
        const float* muB = mu_r + h * 512 + tg * 4;
        const float* wB  = w_r  + h * 512 + tg * 4;
        const float* nsB = smem + tg * 4;
        float tv = tr[tg];
        #pragma unroll 4
        for (int d = 0; d < 32; ++d) {
            float4 m4 = *(const float4*)(muB + d * 16);
            float4 w4 = *(const float4*)(wB  + d * 16);
            float4 n4 = *(const float4*)(nsB + d * 16);
            float d0 = tv - m4.x; a0 = fmaf(w4.x, EXP2(d0 * d0 * n4.x), a0);
            float d1 = tv - m4.y; a1 = fmaf(w4.y, EXP2(d1 * d1 * n4.y), a1);
            float d2 = tv - m4.z; a2 = fmaf(w4.z, EXP2(d2 * d2 * n4.z), a2);
            float d3 = tv - m4.w; a3 = fmaf(w4.w, EXP2(d3 * d3 * n4.w), a3);
        }
    }
    float g = ((a0 + a1) + (a2 + a3)) * (1.0f / 32.0f);
    float* gb = ws + W_GR + (size_t)(b * Hc + h) * (Lc * Lc);
    gb[i * Lc + j] = g;
    if (ti != tj) {
        float* lt = smem + 544;
        __syncthreads();
        lt[di * 17 + dj] = g;
        __syncthreads();
        gb[(tj * 16 + di) * Lc + (ti * 16 + dj)] = lt[dj * 17 + di];
    }
}

// ===========================================================================
// kSP: 32x32 logit tiles. grid (8 jt, 8 it, 16 bh) = 1024 blocks (4/CU).
// logit = S * (P*(2*alpha*g_abs + beta*g_rel) + gamma), in-place on GR.
// ===========================================================================
__global__ void __launch_bounds__(256) kSP(
    const float* __restrict__ x, const float* __restrict__ alpha,
    const float* __restrict__ beta, const float* __restrict__ gamma,
    float* __restrict__ ws)
{
    constexpr int PITCH = 33;
    int jt = blockIdx.x, it = blockIdx.y, bh = blockIdx.z;
    int b = bh >> 3, h = bh & 7;
    int i0 = it * 32, j0 = jt * 32;
    int tid = threadIdx.x;
    __shared__ float sm[4 * 32 * PITCH];
    float* sQ  = sm;                  // [k][i]
    float* sK  = sm + 32 * PITCH;     // [k][j]
    float* sXi = sm + 64 * PITCH;
    float* sXj = sm + 96 * PITCH;
    const float* Q = ws + W_Q;
    const float* K = ws + W_K;

    {
        int r = tid >> 3, c4 = (tid & 7) * 4;
        float4 qv = *(const float4*)(Q + ((size_t)(b * Lc + i0 + r) * DMc + h * DHc + c4));
        float4 kv = *(const float4*)(K + ((size_t)(b * Lc + j0 + r) * DMc + h * DHc + c4));
        float4 xi = *(const float4*)(x + ((size_t)(b * Lc + i0 + r) * DMc + h * DHc + c4));
        float4 xj = *(const float4*)(x + ((size_t)(b * Lc + j0 + r) * DMc + h * DHc + c4));
        const float* q_ = (const float*)&qv; const float* k_ = (const float*)&kv;
        const float* a_ = (const float*)&xi; const float* c_ = (const float*)&xj;
        #pragma unroll
        for (int u = 0; u < 4; ++u) {
            sQ [(c4 + u) * PITCH + r] = q_[u];
            sK [(c4 + u) * PITCH + r] = k_[u];
            sXi[(c4 + u) * PITCH + r] = a_[u];
            sXj[(c4 + u) * PITCH + r] = c_[u];
        }
    }
    __syncthreads();

    int tx = tid & 15, ty = tid >> 4;
    int i2 = ty * 2, j2 = tx * 2;
    float accS[2][2] = {}, accP[2][2] = {};
    #pragma unroll 8
    for (int k = 0; k < 32; ++k) {
        float2 qa = *(const float2*)(sQ  + k * PITCH + i2);
        float2 kb = *(const float2*)(sK  + k * PITCH + j2);
        float2 xa = *(const float2*)(sXi + k * PITCH + i2);
        float2 xb = *(const float2*)(sXj + k * PITCH + j2);
        accS[0][0] = fmaf(qa.x, kb.x, accS[0][0]);
        accS[0][1] = fmaf(qa.x, kb.y, accS[0][1]);
        accS[1][0] = fmaf(qa.y, kb.x, accS[1][0]);
        accS[1][1] = fmaf(qa.y, kb.y, accS[1][1]);
        accP[0][0] = fmaf(xa.x, xb.x, accP[0][0]);
        accP[0][1] = fmaf(xa.x, xb.y, accP[0][1]);
        accP[1][0] = fmaf(xa.y, xb.x, accP[1][0]);
        accP[1][1] = fmaf(xa.y, xb.y, accP[1][1]);
    }

    float la = alpha[h], lb = beta[h], lg = gamma[h];
    float* gb = ws + W_GR + (size_t)bh * (Lc * Lc);
    const float* GA = ws + W_GA;
    #pragma unroll
    for (int u = 0; u < 2; ++u) {
        int i = i0 + i2 + u;
        float ca = 2.0f * la * GA[bh * Lc + i];
        float* addr = gb + (size_t)i * Lc + j0 + j2;
        float2 gr = *(const float2*)addr;
        float2 o;
        o.x = accS[u][0] * fmaf(accP[u][0], fmaf(lb, gr.x, ca), lg);
        o.y = accS[u][1] * fmaf(accP[u][1], fmaf(lb, gr.y, ca), lg);
        *(float2*)addr = o;
    }
}

// ===========================================================================
// kPV: softmax + PV. grid (16 it, 16 bh, 2 half) = 512 blocks (2/CU).
// Each block: 16 rows x 256 logits -> probs (LDS), V d-half staged, PV -> AO.
// ===========================================================================
__global__ void __launch_bounds__(256) kPV(float* __restrict__ ws) {
    int it = blockIdx.x, bh = blockIdx.y, half = blockIdx.z;
    int b = bh >> 3, h = bh & 7;
    int i0 = it * 16;
    int tid = threadIdx.x;
    int ty = tid >> 4, tx = tid & 15;
    __shared__ float sP[16 * 264];
    __shared__ float sV[256 * 17];
    const float* GR = ws + W_GR;
    const float* V = ws + W_V;

    {   // softmax for row (i0+ty), 16 threads per row
        const float* lrow = GR + (size_t)bh * (Lc * Lc) + (size_t)(i0 + ty) * Lc + tx * 16;
        float4 p0 = *(const float4*)(lrow);
        float4 p1 = *(const float4*)(lrow + 4);
        float4 p2 = *(const float4*)(lrow + 8);
        float4 p3 = *(const float4*)(lrow + 12);
        float m = fmaxf(fmaxf(fmaxf(p0.x, p0.y), fmaxf(p0.z, p0.w)),
                        fmaxf(fmaxf(p1.x, p1.y), fmaxf(p1.z, p1.w)));
        m = fmaxf(m, fmaxf(fmaxf(fmaxf(p2.x, p2.y), fmaxf(p2.z, p2.w)),
                           fmaxf(fmaxf(p3.x, p3.y), fmaxf(p3.z, p3.w))));
        #pragma unroll
        for (int s = 1; s < 16; s <<= 1) m = fmaxf(m, __shfl_xor(m, s, 64));
        float4 e0, e1, e2, e3;
        e0.x = EXP2((p0.x - m) * LOG2E); e0.y = EXP2((p0.y - m) * LOG2E);
        e0.z = EXP2((p0.z - m) * LOG2E); e0.w = EXP2((p0.w - m) * LOG2E);
        e1.x = EXP2((p1.x - m) * LOG2E); e1.y = EXP2((p1.y - m) * LOG2E);
        e1.z = EXP2((p1.z - m) * LOG2E); e1.w = EXP2((p1.w - m) * LOG2E);
        e2.x = EXP2((p2.x - m) * LOG2E); e2.y = EXP2((p2.y - m) * LOG2E);
        e2.z = EXP2((p2.z - m) * LOG2E); e2.w = EXP2((p2.w - m) * LOG2E);
        e3.x = EXP2((p3.x - m) * LOG2E); e3.y = EXP2((p3.y - m) * LOG2E);
        e3.z = EXP2((p3.z - m) * LOG2E); e3.w = EXP2((p3.w - m) * LOG2E);
        float sum = ((e0.x + e0.y) + (e0.z + e0.w)) + ((e1.x + e1.y) + (e1.z + e1.w)) +
                    ((e2.x + e2.y) + (e2.z + e2.w)) + ((e3.x + e3.y) + (e3.z + e3.w));
        #pragma unroll
        for (int s = 1; s < 16; s <<= 1) sum += __shfl_xor(sum, s, 64);
        float rs = 1.0f / sum;
        float* prow = sP + ty * 264 + tx * 16;
        e0.x *= rs; e0.y *= rs; e0.z *= rs; e0.w *= rs;
        e1.x *= rs; e1.y *= rs; e1.z *= rs; e1.w *= rs;
        e2.x *= rs; e2.y *= rs; e2.z *= rs; e2.w *= rs;
        e3.x *= rs; e3.y *= rs; e3.z *= rs; e3.w *= rs;
        *(float4*)(prow)      = e0;
        *(float4*)(prow + 4)  = e1;
        *(float4*)(prow + 8)  = e2;
        *(float4*)(prow + 12) = e3;
    }
    {   // stage V half-slice [256 j][16 d] pitch 17
        int r = tid >> 2, c4 = (tid & 3) * 4;
        #pragma unroll
        for (int u = 0; u < 4; ++u) {
            int j = r + u * 64;
            float4 vv = *(const float4*)(V + ((size_t)(b * Lc + j) * DMc
                                              + h * DHc + half * 16 + c4));
            sV[j * 17 + c4 + 0] = vv.x;
            sV[j * 17 + c4 + 1] = vv.y;
            sV[j * 17 + c4 + 2] = vv.z;
            sV[j * 17 + c4 + 3] = vv.w;
        }
    }
    __syncthreads();
    {   // PV: thread (row=ty, d=tx)
        float a0 = 0.f, a1 = 0.f, a2 = 0.f, a3 = 0.f;
        #pragma unroll 4
        for (int j4 = 0; j4 < 256; j4 += 4) {
            float4 p4 = *(const float4*)(sP + ty * 264 + j4);
            a0 = fmaf(p4.x, sV[(j4 + 0) * 17 + tx], a0);
            a1 = fmaf(p4.y, sV[(j4 + 1) * 17 + tx], a1);
            a2 = fmaf(p4.z, sV[(j4 + 2) * 17 + tx], a2);
            a3 = fmaf(p4.w, sV[(j4 + 3) * 17 + tx], a3);
        }
        ws[W_AO + (size_t)(b * Lc + i0 + ty) * DMc + h * DHc + half * 16 + tx] =
            (a0 + a1) + (a2 + a3);
    }
}

// ===========================================================================
// kOut: out = AO @ WO^T + bO. grid (16,8).
// ===========================================================================
__global__ void __launch_bounds__(256) kOut(const float* __restrict__ ws_c,
                                            const float* __restrict__ WO,
                                            const float* __restrict__ bO,
                                            float* __restrict__ out) {
    __shared__ float smem[2 * 16 * 33];
    gemm32(ws_c + W_AO, WO, out, bO, 1.0f, blockIdx.x * 32, blockIdx.y * 32, smem);
}

// ===========================================================================
extern "C" void kernel_launch(void* const* d_in, const int* in_sizes, int n_in,
                              void* d_out, int out_size, void* d_ws, size_t ws_size,
                              hipStream_t stream) {
    (void)in_sizes; (void)n_in; (void)out_size; (void)ws_size;
    const float* x      = (const float*)d_in[0];
    const float* t      = (const float*)d_in[1];
    const float* WQ     = (const float*)d_in[2];
    const float* WK     = (const float*)d_in[3];
    const float* WV     = (const float*)d_in[4];
    const float* WO     = (const float*)d_in[5];
    const float* bO     = (const float*)d_in[6];
    const float* mu_abs = (const float*)d_in[7];
    const float* sg_abs = (const float*)d_in[8];
    const float* w_abs  = (const float*)d_in[9];
    const float* mu_rel = (const float*)d_in[10];
    const float* sg_rel = (const float*)d_in[11];
    const float* w_rel  = (const float*)d_in[12];
    const float* alpha  = (const float*)d_in[13];
    const float* beta   = (const float*)d_in[14];
    const float* gamma  = (const float*)d_in[15];
    float* out = (float*)d_out;
    float* ws = (float*)d_ws;

    kA<<<dim3(2624), dim3(256), 0, stream>>>(x, t, WQ, WK, WV,
                                             mu_abs, sg_abs, w_abs,
                                             mu_rel, sg_rel, w_rel, ws);
    kSP<<<dim3(8, 8, 16), dim3(256), 0, stream>>>(x, alpha, beta, gamma, ws);
    kPV<<<dim3(16, 16, 2), dim3(256), 0, stream>>>(ws);
    kOut<<<dim3(16, 8), dim3(256), 0, stream>>>(ws, WO, bO, out);
}